// Round 14
// baseline (42.463 us; speedup 1.0000x reference)
//
#include <hip/hip_runtime.h>

#define N_NODES 10000
#define IN_DIM  256
#define OUT_DIM 64
#define ALPHA   0.2f
#define CAPS    128   // hash-slot capacity/row, pow2 (max distinct deg ~66 << 128)
#define NBG     625   // gemm blocks (625 x 16 rows = 10000)

typedef __attribute__((ext_vector_type(8))) short short8v;  // 8 bf16 (4 VGPRs)
typedef __attribute__((ext_vector_type(4))) float f32x4;    // 4 fp32 acc

__device__ __forceinline__ ushort f2bf(float f) {
    unsigned u = __float_as_uint(f);
    return (ushort)((u + 0x7FFFu + ((u >> 16) & 1u)) >> 16);   // RNE
}
__device__ __forceinline__ float bf2f(ushort u) {
    return __uint_as_float((unsigned)u << 16);
}

// ---------------------------------------------------------------------------
// Dispatch 0 (k_prep): clear 5MB hash-slot table to -1 (int4, HBM-bound ~1us)
// + build bf16 W-fragment table Wf (32KB, L2-resident).
// Fragment order: elem j of Wf[((s*4+ct)*64 + g*16+li)] = W[32s+8g+j][16ct+li]
// -> same (g,j)->k map as the A-fragment (consistent k-permutation cancels).
// ---------------------------------------------------------------------------
__global__ __launch_bounds__(256) void k_prep(const float* __restrict__ W,
                                              int4* __restrict__ slots4,
                                              ushort* __restrict__ Wf) {
    const int gid = blockIdx.x * 256 + threadIdx.x;   // 256 blocks -> 65536 threads
    const int4 neg = make_int4(-1, -1, -1, -1);
    for (int i = gid; i < N_NODES * CAPS / 4; i += 65536) slots4[i] = neg;
    for (int w = gid; w < IN_DIM * OUT_DIM; w += 65536) {
        int k = w >> 6, c = w & 63;
        int s = k >> 5, k5 = k & 31, g = k5 >> 3, j = k5 & 7;
        int ct = c >> 4, li = c & 15;
        Wf[(((s * 4 + ct) * 64) + (g * 16 + li)) * 8 + j] = f2bf(W[w]);
    }
}

// ---------------------------------------------------------------------------
// Dispatch 1 (fused, heterogeneous blocks):
//   blocks [0, 625): bf16-MFMA GEMM Wh=X@W (stored bf16) + scores es/ed.
//   blocks [625, 938): edge scatter, 4 edges/thread, HASH-PLACED into the
//     per-row slot table keyed by dst (atomicCAS(-1->d); prev==d => duplicate
//     dropped, matching reference .at[].set counting each pair once).
// Round-3 lesson: no grid.sync() fusion (69->240us). Rounds 5-7: fp32-VALU
// GEMM latency-bound (30-46us); MFMA fixed it (R8). C/D layout m89-verified:
// col=lane&15, row=(lane>>4)*4+reg.
// ---------------------------------------------------------------------------
__global__ __launch_bounds__(256) void k_fused(const float* __restrict__ X,
                                               const ushort* __restrict__ Wf,
                                               const float* __restrict__ a,
                                               const int* __restrict__ src,
                                               const int* __restrict__ dst,
                                               int E,
                                               ushort* __restrict__ Whb,
                                               float* __restrict__ es,
                                               float* __restrict__ ed,
                                               int* __restrict__ slots) {
    const int t = threadIdx.x;
    const int b = blockIdx.x;

    if (b >= NBG) {
        // ---- scatter role: four edges per thread, hash-dedupe placement ----
        int i0 = (b - NBG) * 1024 + t;
#pragma unroll
        for (int u = 0; u < 4; ++u) {
            int i = i0 + u * 256;
            if (i < E) {
                int s = src[i], d = dst[i];
                int* row = slots + (size_t)s * CAPS;
                unsigned h = ((unsigned)d * 2654435761u) >> 25;   // top 7 bits
                for (int it = 0; it < CAPS; ++it) {
                    int prev = atomicCAS(&row[h], -1, d);
                    if (prev == -1 || prev == d) break;   // placed, or duplicate
                    h = (h + 1) & (CAPS - 1);
                }
            }
        }
        return;
    }

    // ---- gemm role ----
    __shared__ float les[16], led[16];
    if (t < 16) { les[t] = 0.f; led[t] = 0.f; }
    __syncthreads();

    const int wave = t >> 6;          // col-tile ct
    const int lane = t & 63;
    const int g = lane >> 4, li = lane & 15;
    const int row0 = b * 16;          // 625 * 16 = 10000 exactly
    const float* __restrict__ xrow = X + (size_t)(row0 + li) * IN_DIM + g * 8;
    const short8v* __restrict__ Wfrag = (const short8v*)Wf;

    f32x4 acc = {0.f, 0.f, 0.f, 0.f};
#pragma unroll
    for (int s = 0; s < 8; ++s) {
        float4 xa = *(const float4*)(xrow + s * 32);
        float4 xb = *(const float4*)(xrow + s * 32 + 4);
        short8v af;
        af[0] = (short)f2bf(xa.x); af[1] = (short)f2bf(xa.y);
        af[2] = (short)f2bf(xa.z); af[3] = (short)f2bf(xa.w);
        af[4] = (short)f2bf(xb.x); af[5] = (short)f2bf(xb.y);
        af[6] = (short)f2bf(xb.z); af[7] = (short)f2bf(xb.w);
        short8v bfv = Wfrag[(s * 4 + wave) * 64 + lane];   // 16B coalesced, L2
        acc = __builtin_amdgcn_mfma_f32_16x16x32_bf16(af, bfv, acc, 0, 0, 0);
    }

    const int colC = wave * 16 + li;
    const float asrc = a[colC];
    const float adst = a[OUT_DIM + colC];
#pragma unroll
    for (int j = 0; j < 4; ++j) {
        int row = row0 + g * 4 + j;
        float v = acc[j];
        Whb[(size_t)row * OUT_DIM + colC] = f2bf(v);
        float se = v * asrc, sd = v * adst;
        se += __shfl_xor(se, 1, 64); sd += __shfl_xor(sd, 1, 64);
        se += __shfl_xor(se, 2, 64); sd += __shfl_xor(sd, 2, 64);
        se += __shfl_xor(se, 4, 64); sd += __shfl_xor(sd, 4, 64);
        se += __shfl_xor(se, 8, 64); sd += __shfl_xor(sd, 8, 64);
        if (li == 0) {
            atomicAdd(&les[g * 4 + j], se);
            atomicAdd(&led[g * 4 + j], sd);
        }
    }
    __syncthreads();
    if (t < 16) { es[row0 + t] = les[t]; ed[row0 + t] = led[t]; }
}

// ---------------------------------------------------------------------------
// Dispatch 2: 4 rows per 256-thread block (2500 blocks — 4x less dispatch
// ramp than 10000x64). Each wave owns one row; ALL LDS traffic is wave-local
// (per-wave segments) so there is NO __syncthreads — wave_barrier() only
// pins compiler ordering (AMD LDS ops of a wave complete in issue order),
// keeping the deg-0 early-return safe. Slots pre-deduped by scatter ->
// ballot/popc compaction; dual-half ushort2 PV gathers; float2 store.
// ---------------------------------------------------------------------------
__global__ __launch_bounds__(256) void k_attn_hash(const int* __restrict__ slots,
                                                   const float* __restrict__ es,
                                                   const float* __restrict__ ed,
                                                   const ushort* __restrict__ Whb,
                                                   float* __restrict__ out) {
    const int wave = threadIdx.x >> 6;
    const int lane = threadIdx.x & 63;
    const int r = blockIdx.x * 4 + wave;          // 2500 * 4 = 10000 exactly

    __shared__ int   sdst[4][CAPS];
    __shared__ float sp[4][CAPS];

    int d0 = slots[(size_t)r * CAPS + lane];
    int d1 = slots[(size_t)r * CAPS + 64 + lane];
    const bool v0 = d0 >= 0, v1 = d1 >= 0;
    const unsigned long long mask0 = __ballot(v0);
    const unsigned long long mask1 = __ballot(v1);

    if ((mask0 | mask1) == 0ull) {
        // row has no edges: softmax of all-NEG_FILL is uniform -> column mean
        float acc = 0.f;
        for (int j = 0; j < N_NODES; ++j) acc += bf2f(Whb[(size_t)j * OUT_DIM + lane]);
        out[(size_t)r * OUT_DIM + lane] = acc / (float)N_NODES;
        return;                                    // safe: no block barriers below
    }

    const float er = es[r];
    float t0 = er + ed[v0 ? d0 : 0];  t0 = t0 > 0.f ? t0 : ALPHA * t0;
    float t1 = er + ed[v1 ? d1 : 0];  t1 = t1 > 0.f ? t1 : ALPHA * t1;
    float e0 = v0 ? t0 : -INFINITY;
    float e1 = v1 ? t1 : -INFINITY;

    float m = fmaxf(e0, e1);
#pragma unroll
    for (int o = 32; o > 0; o >>= 1) m = fmaxf(m, __shfl_xor(m, o, 64));

    float p0 = v0 ? __expf(e0 - m) : 0.f;
    float p1 = v1 ? __expf(e1 - m) : 0.f;
    float ssum = p0 + p1;
#pragma unroll
    for (int o = 32; o > 0; o >>= 1) ssum += __shfl_xor(ssum, o, 64);

    // ballot/popc compaction into this wave's LDS segment
    const unsigned long long below = (1ull << lane) - 1ull;
    const int cnt0 = __popcll(mask0);
    if (v0) {
        int p = __popcll(mask0 & below);
        sdst[wave][p] = d0; sp[wave][p] = p0;
    }
    if (v1) {
        int p = cnt0 + __popcll(mask1 & below);
        sdst[wave][p] = d1; sp[wave][p] = p1;
    }
    const int count = cnt0 + __popcll(mask1);
    __builtin_amdgcn_wave_barrier();   // compiler fence; wave LDS ops are in-order

    // dual-half PV: half h2 takes entries i%2==h2; lane covers columns
    // (2c, 2c+1) via ushort2; 8 pairs (16 entries) in flight per batch.
    const int h2 = lane >> 5;
    const int c  = lane & 31;
    const ushort2* __restrict__ W2 = (const ushort2*)Whb;   // row stride 32
    float ax = 0.f, ay = 0.f;
    const int npairs = count >> 1;
    int ip = 0;
    for (; ip + 8 <= npairs; ip += 8) {
        float p[8]; int q[8]; ushort2 w[8];
#pragma unroll
        for (int u = 0; u < 8; ++u) {
            int i = 2 * (ip + u) + h2;
            p[u] = sp[wave][i]; q[u] = sdst[wave][i];
        }
#pragma unroll
        for (int u = 0; u < 8; ++u) w[u] = W2[(size_t)q[u] * 32 + c];
#pragma unroll
        for (int u = 0; u < 8; ++u) {
            ax = fmaf(p[u], bf2f(w[u].x), ax);
            ay = fmaf(p[u], bf2f(w[u].y), ay);
        }
    }
    for (; ip < npairs; ++ip) {
        int i = 2 * ip + h2;
        float p = sp[wave][i];
        ushort2 w = W2[(size_t)sdst[wave][i] * 32 + c];
        ax = fmaf(p, bf2f(w.x), ax);
        ay = fmaf(p, bf2f(w.y), ay);
    }
    if ((count & 1) && h2 == 0) {     // odd tail: half 0 only
        int i = count - 1;
        float p = sp[wave][i];
        ushort2 w = W2[(size_t)sdst[wave][i] * 32 + c];
        ax = fmaf(p, bf2f(w.x), ax);
        ay = fmaf(p, bf2f(w.y), ay);
    }
    ax += __shfl_xor(ax, 32, 64);
    ay += __shfl_xor(ay, 32, 64);
    if (h2 == 0) {
        float inv = 1.f / ssum;
        ((float2*)out)[(size_t)r * 32 + c] = make_float2(ax * inv, ay * inv);
    }
}

// ---------------------------------------------------------------------------
extern "C" void kernel_launch(void* const* d_in, const int* in_sizes, int n_in,
                              void* d_out, int out_size, void* d_ws, size_t ws_size,
                              hipStream_t stream) {
    const float* X     = (const float*)d_in[0];
    const int*   edges = (const int*)d_in[1];
    const float* W     = (const float*)d_in[2];
    const float* a     = (const float*)d_in[3];
    float* out = (float*)d_out;

    const int E = in_sizes[1] / 2;
    const int* src = edges;
    const int* dst = edges + E;

    char* ws = (char*)d_ws;
    size_t o = 0;
    auto carve = [&](size_t bytes) -> void* {
        o = (o + 255) & ~(size_t)255;
        void* p = ws + o;
        o += bytes;
        return p;
    };
    ushort* Whb   = (ushort*)carve((size_t)N_NODES * OUT_DIM * 2);
    float*  es    = (float*)carve((size_t)N_NODES * 4);
    float*  ed    = (float*)carve((size_t)N_NODES * 4);
    int*    slots = (int*)carve((size_t)N_NODES * CAPS * 4);
    ushort* Wf    = (ushort*)carve((size_t)IN_DIM * OUT_DIM * 2);

    const int nsc = (E + 1023) / 1024;   // scatter blocks (4 edges/thread) = 313

    // prep (clear slots + Wf) -> fused (gemm || scatter) -> attn. 3 dependent
    // dispatch levels (clear->scatter->attn, gemm->attn) — minimum achievable
    // without intra-dispatch ordering (R3: grid.sync costs +170us on 8-XCD).
    k_prep     <<<256, 256, 0, stream>>>(W, (int4*)slots, Wf);
    k_fused    <<<NBG + nsc, 256, 0, stream>>>(X, Wf, a, src, dst, E,
                                               Whb, es, ed, slots);
    k_attn_hash<<<2500, 256, 0, stream>>>(slots, es, ed, Whb, out);
}